// Round 3
// baseline (322.994 us; speedup 1.0000x reference)
//
#include <hip/hip_runtime.h>

// VQ-VAE nearest-code lookup: MFMA filter (code-granular) + coalesced fp32 refine.
// N=65536 tokens, K=1024 codes, D=256, fp32 in/out.
// out layout (flat f32): values[N*256] | indices[N] (as float) | vectors[N*256]
//
// prep : weight -> bf16 (RTNE), sqr[k] fp32, zero worklist counter
// pass1: R6b (R6 resubmit + hardening; R6 bench was an infra failure):
//        (a) bijective LDS placement: stage chunk (code cc, chunk ch) at
//        slot = half*512 + kt*64 + quad*16 + col, so every ds_read_b128 is
//        base + lane*16 -> zero bank conflicts by construction (R5's 16B XOR
//        couldn't fix the 512B row stride == 0 mod 128B).
//        (b) T3/T4 pipeline: triple-buffered stages, raw s_barrier + counted
//        s_waitcnt vmcnt(4) -- no per-stage vmcnt(0) drain (R5: ~2500cy/stage
//        for ~700cy of work = LDS-pipe + drain dominated).
//        (c) 2x2 wave decomposition: wave = 64 rows x 512 codes -> 4 MFMA per
//        ds_read_b128 (2x arithmetic intensity vs R5), halving LDS traffic.
//        Cross-wave rmin combine via 1KB LDS.
//        phase A: per-row min (registers). phase B: recompute, emit codes with
//        s <= rmin+MARGIN into LDS list, ONE global atomicAdd per block.
//        vmcnt self-heal note: overflow-path atomics cause the compiler to
//        emit vmcnt(0) before using the returned value; subsequent counted
//        waits then pass early but every buffer they guard has already landed
//        (drains are strictly conservative) -> counting stays correct.
// pass2: quarter-wave (16 lanes) per candidate: exact fp32 dot, coalesced;
//        lexicographic (score,idx) u64 atomicMin == np.argmin tie-break.
// pass3: gather weight[idx] -> values & vectors, write indices.
//
// Margin proof: |approx-exact| per score <= 2*2^-9*2*sum|a_i b_i| ~ 1.3 typ,
// <2.5 tail; candidate test needs MARGIN >= 2*err ~ 5; MARGIN=12 -> 2.4x slack.

constexpr int N_TOK = 65536;
constexpr int KC    = 1024;
constexpr int D     = 256;

constexpr size_t IDX_OFF = (size_t)N_TOK * D;   // 16777216 floats
constexpr size_t VEC_OFF = IDX_OFF + N_TOK;     // 16842752 floats
constexpr int    WL_CAP  = 16777216;            // worklist slots in values region

#define MARGIN 12.0f

typedef __attribute__((ext_vector_type(8))) short bf16x8;
typedef __attribute__((ext_vector_type(4))) float f32x4;

__device__ inline unsigned short f2bf(float x) {
    unsigned int u = __float_as_uint(x);
    unsigned int r = (u + 0x7FFFu + ((u >> 16) & 1u)) >> 16;
    return (unsigned short)r;
}

__device__ inline unsigned int fkey(float f) {
    unsigned int b = __float_as_uint(f);
    return (b & 0x80000000u) ? ~b : (b | 0x80000000u);
}

// ---------------- prep: weight -> bf16, sqr, zero counter ----------------
__global__ __launch_bounds__(64)
void vq_prep(const float* __restrict__ w, unsigned short* __restrict__ wbf,
             float* __restrict__ sqr, int* __restrict__ cnt) {
    const int code = blockIdx.x;
    const int lane = threadIdx.x;
    float4 v = ((const float4*)w)[(size_t)code * 64 + lane];
    float s = v.x * v.x + v.y * v.y + v.z * v.z + v.w * v.w;
#pragma unroll
    for (int off = 32; off >= 1; off >>= 1) s += __shfl_xor(s, off, 64);
    unsigned short* d = wbf + (size_t)code * D + lane * 4;
    d[0] = f2bf(v.x); d[1] = f2bf(v.y); d[2] = f2bf(v.z); d[3] = f2bf(v.w);
    if (lane == 0) sqr[code] = s;
    if (code == 0 && lane == 0) *cnt = 0;
}

// ---------------- pass1 ----------------
constexpr int CT   = 32;        // codes per stage (16 KB per buffer)
constexpr int NSTG = KC / CT;   // 32 stages per scan
constexpr int LCAP = 3072;

struct __align__(16) P1Shared {
    unsigned short sbuf[3][CT * D];  // 48 KB triple-buffered B tiles (permuted)
    float sqr[KC];                   // 4 KB
    float rminx[2][128];             // 1 KB cross-wave min exchange
    int   list[LCAP];                // 12 KB
    int   lcnt, gbase;
};                                   // ~65.3 KB -> 2 blocks/CU

// Issue the DMA for one stage into dstbuf. Dest is linear (global_load_lds
// rule); the SOURCE is permuted so that slot(cc,ch) = (cc>>4)*512 +
// (ch>>2)*64 + (ch&3)*16 + (cc&15). Read side then sees slot = wc*512 +
// kt*64 + quad*16 + col == base + lane  ->  conflict-free ds_read_b128.
__device__ __forceinline__ void stage_issue(const char* __restrict__ srcbase,
                                            unsigned short* __restrict__ dstbuf,
                                            const int (&soff)[4], int tid) {
#pragma unroll
    for (int r = 0; r < 4; ++r) {
        __builtin_amdgcn_global_load_lds(
            (const __attribute__((address_space(1))) void*)(srcbase + soff[r]),
            (__attribute__((address_space(3))) void*)(dstbuf + (tid + r * 256) * 8),
            16, 0, 0);
    }
}

template<bool EMIT>
__device__ __forceinline__ void scan(const char* __restrict__ wbfB, P1Shared& sh,
                                     const bf16x8 (&a)[4][8], float (&rmin)[4][4],
                                     int row_base_blk, int wr, int wc,
                                     int tid, int lane, int col, int quad,
                                     const int (&soff)[4],
                                     int* __restrict__ wl, int* __restrict__ cnt) {
    // prologue: 2 stages in flight (8 loads/thread)
    stage_issue(wbfB, sh.sbuf[0], soff, tid);
    stage_issue(wbfB + 16384, sh.sbuf[1], soff, tid);

    for (int s = 0; s < NSTG; ++s) {
        // counted wait: my 4 loads for buffer s are the oldest outstanding
        if (s == NSTG - 1) asm volatile("s_waitcnt vmcnt(0)" ::: "memory");
        else               asm volatile("s_waitcnt vmcnt(4)" ::: "memory");
        __builtin_amdgcn_sched_barrier(0);     // pin: nothing moves above wait
        __builtin_amdgcn_s_barrier();          // raw barrier: no drain
        __builtin_amdgcn_sched_barrier(0);     // pin: no hoist above barrier
        if (s + 2 < NSTG)
            stage_issue(wbfB + (s + 2) * 16384, sh.sbuf[(s + 2) % 3], soff, tid);

        const unsigned short* sb =
            sh.sbuf[s % 3] + wc * 4096 + (quad * 16 + col) * 8;
        bf16x8 b[8];
#pragma unroll
        for (int kt = 0; kt < 8; ++kt)
            b[kt] = *(const bf16x8*)(sb + kt * 512);

        const int c0 = s * CT + wc * 16;       // this wave's 16-code tile base
        const float sq = sh.sqr[c0 + col];
#pragma unroll
        for (int rt = 0; rt < 4; ++rt) {
            f32x4 acc = {0.f, 0.f, 0.f, 0.f};
#pragma unroll
            for (int kt = 0; kt < 8; ++kt)
                acc = __builtin_amdgcn_mfma_f32_16x16x32_bf16(a[rt][kt], b[kt], acc, 0, 0, 0);
            if (!EMIT) {
#pragma unroll
                for (int rg = 0; rg < 4; ++rg)
                    rmin[rt][rg] = fminf(rmin[rt][rg], sq - 2.0f * acc[rg]);
            } else {
#pragma unroll
                for (int rg = 0; rg < 4; ++rg) {
                    const float sc = sq - 2.0f * acc[rg];
                    const bool flag = (sc <= rmin[rt][rg] + MARGIN);
                    unsigned long long mask = __ballot(flag);
                    if (mask) {
                        const int leader = __builtin_ctzll(mask);
                        const int nact   = __popcll(mask);
                        const int prefix = __popcll(mask & ((1ULL << lane) - 1ULL));
                        int wbase = 0;
                        if (lane == leader) wbase = atomicAdd(&sh.lcnt, nact);
                        wbase = __shfl(wbase, leader, 64);
                        if (flag) {
                            const int row  = row_base_blk + wr * 64 + rt * 16 + quad * 4 + rg;
                            const int item = (row << 10) | (c0 + col);
                            const int pos  = wbase + prefix;
                            if (pos < LCAP) {
                                sh.list[pos] = item;
                            } else {            // rare overflow: direct global
                                int g = atomicAdd(cnt, 1);
                                if (g < WL_CAP) wl[g] = item;
                            }
                        }
                    }
                }
            }
        }
    }
}

// 512 blocks x 256 thr. Block: 128 rows x 1024 codes. Wave (wr,wc): rows
// [wr*64,+64) x codes {s*32 + wc*16 + col}.
__global__ __launch_bounds__(256, 2)
void vq_pass1(const float* __restrict__ input, const unsigned short* __restrict__ wbf,
              const float* __restrict__ sqr, int* __restrict__ wl,
              int* __restrict__ cnt, unsigned long long* __restrict__ cand) {
    __shared__ P1Shared sh;

    const int tid  = threadIdx.x;
    const int wave = tid >> 6;
    const int lane = tid & 63;
    const int col  = lane & 15;
    const int quad = lane >> 4;
    const int wr   = wave >> 1;
    const int wc   = wave & 1;
    const int row_base_blk = blockIdx.x * 128;

    if (tid == 0) sh.lcnt = 0;
    ((float4*)sh.sqr)[tid] = ((const float4*)sqr)[tid];   // 1024 f32 -> LDS
    if (tid < 128) cand[row_base_blk + tid] = 0xFFFFFFFFFFFFFFFFULL;

    // per-thread DMA source offsets (bytes within a stage's 16 KB block):
    // invert slot -> (cc,ch):  half=slot>>9, kt=(slot>>6)&7, quad=(slot>>4)&3,
    // col=slot&15;  cc=half*16+col, ch=4*kt+quad;  off = cc*512 + ch*16.
    int soff[4];
#pragma unroll
    for (int r = 0; r < 4; ++r) {
        const int sl = tid + r * 256;
        const int cc = ((sl >> 9) << 4) + (sl & 15);
        const int ch = (((sl >> 6) & 7) << 2) + ((sl >> 4) & 3);
        soff[r] = cc * 512 + ch * 16;
    }

    // A fragments: 4 row-tiles x 8 k-tiles (128 VGPRs)
    bf16x8 a[4][8];
#pragma unroll
    for (int rt = 0; rt < 4; ++rt) {
        const float* ar = input + (size_t)(row_base_blk + wr * 64 + rt * 16 + col) * D;
#pragma unroll
        for (int kt = 0; kt < 8; ++kt) {
            const int k0 = kt * 32 + quad * 8;
            float4 f0 = *(const float4*)(ar + k0);
            float4 f1 = *(const float4*)(ar + k0 + 4);
            bf16x8 v;
            v[0] = (short)f2bf(f0.x); v[1] = (short)f2bf(f0.y);
            v[2] = (short)f2bf(f0.z); v[3] = (short)f2bf(f0.w);
            v[4] = (short)f2bf(f1.x); v[5] = (short)f2bf(f1.y);
            v[6] = (short)f2bf(f1.z); v[7] = (short)f2bf(f1.w);
            a[rt][kt] = v;
        }
    }

    float rmin[4][4];
#pragma unroll
    for (int rt = 0; rt < 4; ++rt)
#pragma unroll
        for (int rg = 0; rg < 4; ++rg) rmin[rt][rg] = 3.4e38f;

    __syncthreads();   // sqr/lcnt visible; full drain -> vmcnt clean at entry

    // ---- phase A: per-row min over this wave's 512 codes ----
    scan<false>((const char*)wbf, sh, a, rmin, row_base_blk, wr, wc,
                tid, lane, col, quad, soff, wl, cnt);

    // butterfly min over the 16 col-lanes (xor 1,2,4,8 stays within quad)
#pragma unroll
    for (int off = 1; off <= 8; off <<= 1)
#pragma unroll
        for (int rt = 0; rt < 4; ++rt)
#pragma unroll
            for (int rg = 0; rg < 4; ++rg)
                rmin[rt][rg] = fminf(rmin[rt][rg], __shfl_xor(rmin[rt][rg], off, 64));

    // ---- cross-wave (wc pair) combine -> full 1024-code min ----
    if (col == 0) {
#pragma unroll
        for (int rt = 0; rt < 4; ++rt)
#pragma unroll
            for (int rg = 0; rg < 4; ++rg)
                sh.rminx[wc][wr * 64 + rt * 16 + quad * 4 + rg] = rmin[rt][rg];
    }
    __syncthreads();   // also fences phase-A sbuf reads before phase-B DMA
#pragma unroll
    for (int rt = 0; rt < 4; ++rt)
#pragma unroll
        for (int rg = 0; rg < 4; ++rg)
            rmin[rt][rg] = fminf(rmin[rt][rg],
                                 sh.rminx[wc ^ 1][wr * 64 + rt * 16 + quad * 4 + rg]);

    // ---- phase B: recompute, emit candidates ----
    scan<true>((const char*)wbf, sh, a, rmin, row_base_blk, wr, wc,
               tid, lane, col, quad, soff, wl, cnt);

    // ---- flush: one global reservation per block ----
    __syncthreads();
    const int n = min(sh.lcnt, LCAP);
    if (tid == 0) sh.gbase = atomicAdd(cnt, n);
    __syncthreads();
    const int base = sh.gbase;
    for (int i = tid; i < n; i += 256) wl[base + i] = sh.list[i];
}

// ---------------- pass2: coalesced exact fp32 refine (16 lanes/cand) ------
__global__ __launch_bounds__(256)
void vq_pass2(const float* __restrict__ input, const float* __restrict__ weight,
              const float* __restrict__ sqr, const int* __restrict__ wl,
              const int* __restrict__ cnt, unsigned long long* __restrict__ cand) {
    const int sw  = threadIdx.x >> 4;       // 16 sub-waves per block
    const int sl  = threadIdx.x & 15;
    const int gsw = blockIdx.x * 16 + sw;
    const int nsw = gridDim.x * 16;
    const int n   = min(*cnt, WL_CAP);
    const float4* in4 = (const float4*)input;
    const float4* w4  = (const float4*)weight;

    for (int e = gsw; e < n; e += nsw) {
        const int ent  = wl[e];             // sub-wave-uniform (broadcast)
        const int row  = ent >> 10;
        const int code = ent & 1023;
        const float4* zr = in4 + (size_t)row * 64;
        const float4* wr = w4 + (size_t)code * 64;
        float s = 0.f;
#pragma unroll
        for (int j = 0; j < 4; ++j) {       // lane sl covers q = sl + 16*j
            float4 za = zr[sl + 16 * j];
            float4 wa = wr[sl + 16 * j];
            s = fmaf(za.x, wa.x, s);
            s = fmaf(za.y, wa.y, s);
            s = fmaf(za.z, wa.z, s);
            s = fmaf(za.w, wa.w, s);
        }
#pragma unroll
        for (int off = 1; off <= 8; off <<= 1) s += __shfl_xor(s, off, 16);
        if (sl == 0) {
            const float score = sqr[code] - 2.0f * s;
            unsigned long long key =
                ((unsigned long long)fkey(score) << 32) | (unsigned int)code;
            atomicMin(&cand[row], key);
        }
    }
}

// ---------------- pass3: gather + write outputs ----------------
__global__ __launch_bounds__(256)
void vq_pass3(const float* __restrict__ weight,
              const unsigned long long* __restrict__ cand,
              float* __restrict__ out) {
    __shared__ int fin[64];
    const int tid  = threadIdx.x;
    const int row0 = blockIdx.x * 64;
    if (tid < 64) {
        int idx = (int)(unsigned int)(cand[row0 + tid] & 0xFFFFFFFFULL);
        fin[tid] = idx;
        out[IDX_OFF + row0 + tid] = (float)idx;
    }
    __syncthreads();
    const float4* w4 = (const float4*)weight;
    float4* out4 = (float4*)out;
#pragma unroll
    for (int k = 0; k < 16; ++k) {
        int i = tid + k * 256;
        int r = i >> 6, q = i & 63;
        float4 v = w4[(size_t)fin[r] * 64 + q];
        size_t o = (size_t)(row0 + r) * 64 + q;
        out4[o] = v;                    // values
        out4[VEC_OFF / 4 + o] = v;      // vectors
    }
}

extern "C" void kernel_launch(void* const* d_in, const int* in_sizes, int n_in,
                              void* d_out, int out_size, void* d_ws, size_t ws_size,
                              hipStream_t stream) {
    const float* input  = (const float*)d_in[0];   // [64,32,32,256] f32
    const float* weight = (const float*)d_in[1];   // [1024,256] f32
    float* out = (float*)d_out;

    // ws layout (~1.04 MB)
    unsigned short* wbf = (unsigned short*)d_ws;                            // 512 KB
    float* sqr = (float*)((char*)d_ws + 524288);                            // 4 KB
    int*   cnt = (int*)((char*)d_ws + 528384);                              // 4 B
    unsigned long long* cand = (unsigned long long*)((char*)d_ws + 532480); // 512 KB

    // worklist lives in out's values region (16.7M ints); pass3 overwrites it
    int* wl = (int*)out;

    vq_prep <<<KC, 64, 0, stream>>>(weight, wbf, sqr, cnt);
    vq_pass1<<<N_TOK / 128, 256, 0, stream>>>(input, wbf, sqr, wl, cnt, cand);
    vq_pass2<<<1024, 256, 0, stream>>>(input, weight, sqr, wl, cnt, cand);
    vq_pass3<<<N_TOK / 64, 256, 0, stream>>>(weight, cand, out);
}

// Round 4
// 286.865 us; speedup vs baseline: 1.1259x; 1.1259x over previous
//
#include <hip/hip_runtime.h>

// VQ-VAE nearest-code lookup, fully fused. N=65536 tokens, K=1024 codes, D=256.
// out layout (flat f32): values[N*256] | indices[N] (as float) | vectors[N*256]
//
// R7: single fused main kernel (filter + refine + output) after R6b post-mortem:
//  * R6b spilled (VGPR=128 vs ~210 needed; +21MB scratch writes) -> switch to
//    mfma_f32_32x32x16_bf16, wave = 32 rows x all 1024 codes: A-frags 64 VGPR
//    (not 128), ~160 total -> no spill; 32x32 rate 2382 TF vs 16x16's 2075;
//    rows partition waves -> no cross-wave rmin combine; input read once.
//  * keep: bijective LDS placement (slot = ch*32 + code; every ds_read_b128
//    is base + lane*16 -> 0 bank conflicts, verified R6b), triple-buffered
//    global_load_lds + raw s_barrier + counted s_waitcnt vmcnt(4).
//  * fuse pass2/pass3: candidates are block-local (rows block-exclusive) ->
//    refine from LDS list (16-lane sub-wave per candidate, exact fp32 dot,
//    lexicographic u64 LDS atomicMin == np.argmin tie-break), then gather
//    weight[idx] and write values/vectors/indices. Kills global worklist
//    round-trip, global cand array, 2 dispatch gaps, ~160MB cold re-reads
//    (non-pass1 time was ~175us of R6b's 323).
//  * overflow (list > LCAP, 11x headroom vs measured): entries -> global owl;
//    vq_cleanup fully recomputes those rows (normally *cnt==0, exits).
//
// Margin proof: |approx-exact| per score <= 2*2^-9*2*sum|a_i b_i| ~ 1.3 typ,
// <2.5 tail; candidate test needs MARGIN >= 2*err ~ 5; MARGIN=12 -> 2.4x slack.
// Phase B recomputes bitwise-identical scores (same frags, same MFMA), so each
// row's approx-min code is always emitted.

constexpr int N_TOK = 65536;
constexpr int KC    = 1024;
constexpr int D     = 256;

constexpr size_t IDX_OFF = (size_t)N_TOK * D;   // 16777216 floats
constexpr size_t VEC_OFF = IDX_OFF + N_TOK;     // 16842752 floats
constexpr int    OWL_CAP = 131072;              // overflow list slots (512 KB ws)

#define MARGIN 12.0f

typedef __attribute__((ext_vector_type(8)))  short bf16x8;
typedef __attribute__((ext_vector_type(4)))  float f32x4;
typedef __attribute__((ext_vector_type(16))) float f32x16;

__device__ inline unsigned short f2bf(float x) {
    unsigned int u = __float_as_uint(x);
    unsigned int r = (u + 0x7FFFu + ((u >> 16) & 1u)) >> 16;
    return (unsigned short)r;
}

__device__ inline unsigned int fkey(float f) {
    unsigned int b = __float_as_uint(f);
    return (b & 0x80000000u) ? ~b : (b | 0x80000000u);
}

// ---------------- prep: weight -> bf16, sqr, zero counter ----------------
__global__ __launch_bounds__(64)
void vq_prep(const float* __restrict__ w, unsigned short* __restrict__ wbf,
             float* __restrict__ sqr, int* __restrict__ cnt) {
    const int code = blockIdx.x;
    const int lane = threadIdx.x;
    float4 v = ((const float4*)w)[(size_t)code * 64 + lane];
    float s = v.x * v.x + v.y * v.y + v.z * v.z + v.w * v.w;
#pragma unroll
    for (int off = 32; off >= 1; off >>= 1) s += __shfl_xor(s, off, 64);
    unsigned short* d = wbf + (size_t)code * D + lane * 4;
    d[0] = f2bf(v.x); d[1] = f2bf(v.y); d[2] = f2bf(v.z); d[3] = f2bf(v.w);
    if (lane == 0) sqr[code] = s;
    if (code == 0 && lane == 0) *cnt = 0;
}

// ---------------- main: filter + refine + output ----------------
constexpr int CT   = 32;        // codes per stage (16 KB per buffer)
constexpr int NSTG = KC / CT;   // 32 stages per scan
constexpr int LCAP = 4096;

struct __align__(16) P1Shared {
    unsigned short sbuf[3][CT * D];  // 48 KB triple-buffered B tiles (permuted)
    float sqr[KC];                   // 4 KB
    int   list[LCAP];                // 16 KB (reused as fin[] in output phase)
    unsigned long long lcand[128];   // 1 KB per-row (score,code) running min
    int   lcnt;
};                                   // ~69.1 KB -> 2 blocks/CU

// Stage CT codes into dstbuf. Dest linear (global_load_lds rule); SOURCE is
// permuted: slot s holds (code = s&31, kchunk = s>>5). Read side: frag kt of
// lane l sits at slot kt*64 + l  ->  base + lane*16, conflict-free b128.
__device__ __forceinline__ void stage_issue(const char* __restrict__ srcbase,
                                            unsigned short* __restrict__ dstbuf,
                                            const int (&soff)[4], int tid) {
#pragma unroll
    for (int r = 0; r < 4; ++r) {
        __builtin_amdgcn_global_load_lds(
            (const __attribute__((address_space(1))) void*)(srcbase + soff[r]),
            (__attribute__((address_space(3))) void*)(dstbuf + (tid + r * 256) * 8),
            16, 0, 0);
    }
}

template<bool EMIT>
__device__ __forceinline__ void scan(const char* __restrict__ wbfB, P1Shared& sh,
                                     const bf16x8 (&afr)[16], float (&rmin)[16],
                                     int row_base_blk, int wave, int lane,
                                     int cl /*lane&31*/, int hi /*lane>>5*/,
                                     int tid, const int (&soff)[4],
                                     int* __restrict__ owl, int* __restrict__ cnt) {
    // prologue: 2 stages in flight (8 loads/thread)
    stage_issue(wbfB, sh.sbuf[0], soff, tid);
    stage_issue(wbfB + 16384, sh.sbuf[1], soff, tid);

    for (int s = 0; s < NSTG; ++s) {
        // counted wait: my 4 loads for buffer s are the oldest outstanding
        if (s == NSTG - 1) asm volatile("s_waitcnt vmcnt(0)" ::: "memory");
        else               asm volatile("s_waitcnt vmcnt(4)" ::: "memory");
        __builtin_amdgcn_sched_barrier(0);
        __builtin_amdgcn_s_barrier();          // raw barrier: no drain
        __builtin_amdgcn_sched_barrier(0);
        if (s + 2 < NSTG)
            stage_issue(wbfB + (s + 2) * 16384, sh.sbuf[(s + 2) % 3], soff, tid);

        const unsigned short* sb = sh.sbuf[s % 3] + (size_t)lane * 8;
        f32x16 acc = {0.f,0.f,0.f,0.f, 0.f,0.f,0.f,0.f,
                      0.f,0.f,0.f,0.f, 0.f,0.f,0.f,0.f};
#pragma unroll
        for (int h = 0; h < 2; ++h) {          // 2 halves keep b live-range at 32 regs
            bf16x8 b[8];
#pragma unroll
            for (int kk = 0; kk < 8; ++kk)
                b[kk] = *(const bf16x8*)(sb + (h * 8 + kk) * 512);
#pragma unroll
            for (int kk = 0; kk < 8; ++kk)
                acc = __builtin_amdgcn_mfma_f32_32x32x16_bf16(afr[h * 8 + kk], b[kk], acc, 0, 0, 0);
        }

        const int c0 = s * CT;
        const float sq = sh.sqr[c0 + cl];
#pragma unroll
        for (int r = 0; r < 16; ++r) {
            const float sc = sq - 2.0f * acc[r];
            if (!EMIT) {
                rmin[r] = fminf(rmin[r], sc);
            } else {
                const bool flag = (sc <= rmin[r] + MARGIN);
                unsigned long long mask = __ballot(flag);
                if (mask) {
                    const int leader = __builtin_ctzll(mask);
                    const int nact   = __popcll(mask);
                    const int prefix = __popcll(mask & ((1ULL << lane) - 1ULL));
                    int wbase = 0;
                    if (lane == leader) wbase = atomicAdd(&sh.lcnt, nact);
                    wbase = __shfl(wbase, leader, 64);
                    if (flag) {
                        // C layout (m74-verified): col=lane&31, row=(r&3)+8*(r>>2)+4*hi
                        const int lrow = wave * 32 + (r & 3) + 8 * (r >> 2) + 4 * hi;
                        const int pos  = wbase + prefix;
                        if (pos < LCAP) {
                            sh.list[pos] = (lrow << 10) | (c0 + cl);
                        } else {              // ~never: global overflow list
                            int g = atomicAdd(cnt, 1);
                            if (g < OWL_CAP)
                                owl[g] = ((row_base_blk + lrow) << 10) | (c0 + cl);
                        }
                    }
                }
            }
        }
    }
}

// 512 blocks x 256 thr. Block: 128 rows x 1024 codes. Wave w: rows [w*32,+32).
__global__ __launch_bounds__(256, 1)
void vq_main(const float* __restrict__ input, const float* __restrict__ weight,
             const unsigned short* __restrict__ wbf, const float* __restrict__ sqr,
             int* __restrict__ cnt, int* __restrict__ owl, float* __restrict__ out) {
    __shared__ P1Shared sh;

    const int tid  = threadIdx.x;
    const int wave = tid >> 6;
    const int lane = tid & 63;
    const int cl   = lane & 31;
    const int hi   = lane >> 5;
    const int row_base_blk = blockIdx.x * 128;

    if (tid == 0) sh.lcnt = 0;
    if (tid < 128) sh.lcand[tid] = 0xFFFFFFFFFFFFFFFFULL;
    ((float4*)sh.sqr)[tid] = ((const float4*)sqr)[tid];   // 1024 f32 -> LDS

    // per-thread DMA source offsets within a 16 KB stage: slot = tid + r*256;
    // code = slot&31, kchunk = slot>>5; off = code*512 + kchunk*16 bytes.
    int soff[4];
#pragma unroll
    for (int r = 0; r < 4; ++r) {
        const int sl = tid + r * 256;
        soff[r] = (sl & 31) * 512 + (sl >> 5) * 16;
    }

    // A fragments, 32x32x16 shape: row = lane&31, k = kt*16 + hi*8 + j.
    // (Any shared A/B k-permutation cancels in the dot; C layout is verified.)
    bf16x8 afr[16];
    {
        const float* ar = input + (size_t)(row_base_blk + wave * 32 + cl) * D;
#pragma unroll
        for (int kt = 0; kt < 16; ++kt) {
            const int k0 = kt * 16 + hi * 8;
            float4 f0 = *(const float4*)(ar + k0);
            float4 f1 = *(const float4*)(ar + k0 + 4);
            bf16x8 v;
            v[0] = (short)f2bf(f0.x); v[1] = (short)f2bf(f0.y);
            v[2] = (short)f2bf(f0.z); v[3] = (short)f2bf(f0.w);
            v[4] = (short)f2bf(f1.x); v[5] = (short)f2bf(f1.y);
            v[6] = (short)f2bf(f1.z); v[7] = (short)f2bf(f1.w);
            afr[kt] = v;
        }
    }

    float rmin[16];
#pragma unroll
    for (int r = 0; r < 16; ++r) rmin[r] = 3.4e38f;

    __syncthreads();   // LDS init visible; full drain -> vmcnt clean at entry

    // ---- phase A: per-row min over all 1024 codes (rows wave-local) ----
    scan<false>((const char*)wbf, sh, afr, rmin, row_base_blk, wave, lane,
                cl, hi, tid, soff, owl, cnt);

    // butterfly min over the 32 code-lanes (rows owned per-lane depend on hi only)
#pragma unroll
    for (int off = 1; off <= 16; off <<= 1)
#pragma unroll
        for (int r = 0; r < 16; ++r)
            rmin[r] = fminf(rmin[r], __shfl_xor(rmin[r], off, 64));

    __syncthreads();   // all waves done reading phase-A sbuf before phase-B DMA

    // ---- phase B: recompute, emit candidates into LDS list ----
    scan<true>((const char*)wbf, sh, afr, rmin, row_base_blk, wave, lane,
               cl, hi, tid, soff, owl, cnt);

    __syncthreads();   // list complete

    // ---- refine: exact fp32 dot per candidate, 16 lanes each ----
    {
        const int n  = min(sh.lcnt, LCAP);
        const int sw = tid >> 4;
        const int sl = tid & 15;
        const float4* in4 = (const float4*)input;
        const float4* w4  = (const float4*)weight;
        for (int e = sw; e < n; e += 16) {
            const int ent  = sh.list[e];
            const int lrow = ent >> 10;
            const int code = ent & 1023;
            const float4* zr = in4 + (size_t)(row_base_blk + lrow) * 64;
            const float4* wr = w4 + (size_t)code * 64;
            float s = 0.f;
#pragma unroll
            for (int j = 0; j < 4; ++j) {
                float4 za = zr[sl + 16 * j];
                float4 wa = wr[sl + 16 * j];
                s = fmaf(za.x, wa.x, s);
                s = fmaf(za.y, wa.y, s);
                s = fmaf(za.z, wa.z, s);
                s = fmaf(za.w, wa.w, s);
            }
#pragma unroll
            for (int off = 1; off <= 8; off <<= 1) s += __shfl_xor(s, off, 16);
            if (sl == 0) {
                const float score = sh.sqr[code] - 2.0f * s;
                unsigned long long key =
                    ((unsigned long long)fkey(score) << 32) | (unsigned int)code;
                atomicMin(&sh.lcand[lrow], key);
            }
        }
    }
    __syncthreads();

    // ---- output: indices + gather weight[idx] -> values & vectors ----
    if (tid < 128) {
        const int idx = (int)(sh.lcand[tid] & 1023ULL);
        sh.list[tid] = idx;                                  // fin[]
        out[IDX_OFF + row_base_blk + tid] = (float)idx;
    }
    __syncthreads();
    {
        const float4* w4 = (const float4*)weight;
        float4* out4 = (float4*)out;
        const int q = tid & 63;
#pragma unroll 4
        for (int it = 0; it < 32; ++it) {
            const int lr  = it * 4 + (tid >> 6);
            const int idx = sh.list[lr];
            const size_t grow = (size_t)(row_base_blk + lr);
            float4 v = w4[(size_t)idx * 64 + q];
            out4[grow * 64 + q] = v;                  // values
            out4[VEC_OFF / 4 + grow * 64 + q] = v;    // vectors
        }
    }
}

// ---------------- cleanup: full exact redo of overflow rows (normally 0) ----
__global__ __launch_bounds__(256)
void vq_cleanup(const float* __restrict__ input, const float* __restrict__ weight,
                const float* __restrict__ sqr, const int* __restrict__ owl,
                const int* __restrict__ cnt, float* __restrict__ out) {
    const int m = min(*cnt, OWL_CAP);
    if (m == 0) return;
    __shared__ float zrow[D];
    __shared__ unsigned long long best;
    const int tid = threadIdx.x;
    for (int e = blockIdx.x; e < m; e += gridDim.x) {
        const int grow = owl[e] >> 10;
        if (tid == 0) best = 0xFFFFFFFFFFFFFFFFULL;
        if (tid < 64) ((float4*)zrow)[tid] = ((const float4*)input)[(size_t)grow * 64 + tid];
        __syncthreads();
        for (int cc = 0; cc < 4; ++cc) {
            const int code = tid * 4 + cc;
            const float4* wr = (const float4*)weight + (size_t)code * 64;
            float s = 0.f;
            for (int k = 0; k < 64; ++k) {
                float4 wa = wr[k];
                s = fmaf(zrow[4 * k],     wa.x, s);
                s = fmaf(zrow[4 * k + 1], wa.y, s);
                s = fmaf(zrow[4 * k + 2], wa.z, s);
                s = fmaf(zrow[4 * k + 3], wa.w, s);
            }
            const float score = sqr[code] - 2.0f * s;
            unsigned long long key =
                ((unsigned long long)fkey(score) << 32) | (unsigned int)code;
            atomicMin(&best, key);
        }
        __syncthreads();
        const int idx = (int)(best & 1023ULL);
        if (tid == 0) out[IDX_OFF + grow] = (float)idx;
        if (tid < 64) {
            float4 v = ((const float4*)weight)[(size_t)idx * 64 + tid];
            ((float4*)out)[(size_t)grow * 64 + tid] = v;
            ((float4*)out)[VEC_OFF / 4 + (size_t)grow * 64 + tid] = v;
        }
        __syncthreads();
    }
}

extern "C" void kernel_launch(void* const* d_in, const int* in_sizes, int n_in,
                              void* d_out, int out_size, void* d_ws, size_t ws_size,
                              hipStream_t stream) {
    const float* input  = (const float*)d_in[0];   // [64,32,32,256] f32
    const float* weight = (const float*)d_in[1];   // [1024,256] f32
    float* out = (float*)d_out;

    // ws layout (~1.04 MB)
    unsigned short* wbf = (unsigned short*)d_ws;                  // 512 KB
    float* sqr = (float*)((char*)d_ws + 524288);                  // 4 KB
    int*   cnt = (int*)((char*)d_ws + 528384);                    // 4 B
    int*   owl = (int*)((char*)d_ws + 532480);                    // 512 KB overflow list

    vq_prep   <<<KC, 64, 0, stream>>>(weight, wbf, sqr, cnt);
    vq_main   <<<N_TOK / 128, 256, 0, stream>>>(input, weight, wbf, sqr, cnt, owl, out);
    vq_cleanup<<<64, 256, 0, stream>>>(input, weight, sqr, owl, cnt, out);
}